// Round 4
// baseline (15862.914 us; speedup 1.0000x reference)
//
#include <hip/hip_runtime.h>
#include <hip/hip_bf16.h>

typedef float f32x4 __attribute__((ext_vector_type(4)));
typedef __bf16 bf16x8 __attribute__((ext_vector_type(8)));
typedef short s16x8 __attribute__((ext_vector_type(8)));
typedef unsigned short u16;

constexpr int Bb = 256, Tt = 128, Ff = 256, Hh = 512;
constexpr int TF = Tt * Ff;                       // 32768
constexpr long OFF_RECON = (long)Bb * Tt * Ff;    // 8388608
constexpr long OFF_H     = 2L * Bb * Tt * Ff;     // 16777216
constexpr long OFF_LOSS  = OFF_H + (long)Bb * Hh; // 16908288

__device__ inline float sigf(float v){ return 1.f / (1.f + expf(-v)); }
__device__ inline u16 f2b(float f){
  unsigned u = __float_as_uint(f);
  u += 0x7fffu + ((u >> 16) & 1u);   // RNE
  return (u16)(u >> 16);
}
__device__ inline float b2f(u16 b){ return __uint_as_float(((unsigned)b) << 16); }

__device__ inline f32x4 mfma16(bf16x8 a, bf16x8 b, f32x4 c){
  return __builtin_amdgcn_mfma_f32_16x16x32_bf16(a, b, c, 0, 0, 0);
}
__device__ inline bf16x8 ldb8(const u16* p){ return *reinterpret_cast<const bf16x8*>(p); }
__device__ inline bf16x8 cvt8(const float* p){
  const float4 a = ((const float4*)p)[0], b = ((const float4*)p)[1];
  s16x8 r;
  r[0]=f2b(a.x); r[1]=f2b(a.y); r[2]=f2b(a.z); r[3]=f2b(a.w);
  r[4]=f2b(b.x); r[5]=f2b(b.y); r[6]=f2b(b.z); r[7]=f2b(b.w);
  return __builtin_bit_cast(bf16x8, r);
}

// ---------------- hoisted big GEMMs (gamma_h, beta for all t) ----------------
enum { M_GH, M_BETA };

struct P {
  const float *x, *mask, *deltas;
  const float *b_gh, *w_gx, *b_gx, *b_comb;
  const u16 *Wgh, *Wcomb;
  u16 *gammah, *beta;
};

template<int MODE>
__global__ __launch_bounds__(256) void gk(P p)
{
  constexpr int K = (MODE==M_GH) ? 256 : 512;
  const int lane = threadIdx.x & 63;
  const int w = threadIdx.x >> 6;
  const int m0 = blockIdx.y*64 + (w>>1)*32;
  const int n0 = blockIdx.x*64 + (w&1)*32;
  const int fr = lane & 15;
  const int kg = (lane >> 4) << 3;

  f32x4 acc[2][2] = {};
  for (int k = 0; k < K; k += 32) {
    const int kk = k + kg;
    bf16x8 a[2], b[2];
    #pragma unroll
    for (int r = 0; r < 2; ++r) {
      const int mr = m0 + 16*r + fr;
      if constexpr (MODE == M_GH) {
        a[r] = cvt8(p.deltas + (size_t)mr*256 + kk);
      } else {
        if (kk < 256) {
          const float4 d0 = *(const float4*)(p.deltas + (size_t)mr*256 + kk);
          const float4 d1 = *(const float4*)(p.deltas + (size_t)mr*256 + kk + 4);
          const float4 w0 = *(const float4*)(p.w_gx + kk);
          const float4 w1 = *(const float4*)(p.w_gx + kk + 4);
          const float4 g0 = *(const float4*)(p.b_gx + kk);
          const float4 g1 = *(const float4*)(p.b_gx + kk + 4);
          s16x8 v;
          v[0]=f2b(expf(-fmaxf(d0.x*w0.x+g0.x,0.f)));
          v[1]=f2b(expf(-fmaxf(d0.y*w0.y+g0.y,0.f)));
          v[2]=f2b(expf(-fmaxf(d0.z*w0.z+g0.z,0.f)));
          v[3]=f2b(expf(-fmaxf(d0.w*w0.w+g0.w,0.f)));
          v[4]=f2b(expf(-fmaxf(d1.x*w1.x+g1.x,0.f)));
          v[5]=f2b(expf(-fmaxf(d1.y*w1.y+g1.y,0.f)));
          v[6]=f2b(expf(-fmaxf(d1.z*w1.z+g1.z,0.f)));
          v[7]=f2b(expf(-fmaxf(d1.w*w1.w+g1.w,0.f)));
          a[r] = __builtin_bit_cast(bf16x8, v);
        } else {
          a[r] = cvt8(p.mask + (size_t)mr*256 + (kk-256));
        }
      }
    }
    #pragma unroll
    for (int cc = 0; cc < 2; ++cc) {
      const int nr = n0 + 16*cc + fr;
      if constexpr (MODE == M_GH) b[cc] = ldb8(p.Wgh   + (size_t)nr*256 + kk);
      else                        b[cc] = ldb8(p.Wcomb + (size_t)nr*512 + kk);
    }
    #pragma unroll
    for (int r = 0; r < 2; ++r)
      #pragma unroll
      for (int cc = 0; cc < 2; ++cc)
        acc[r][cc] = mfma16(a[r], b[cc], acc[r][cc]);
  }

  #pragma unroll
  for (int r = 0; r < 2; ++r)
    #pragma unroll
    for (int cc = 0; cc < 2; ++cc)
      #pragma unroll
      for (int q = 0; q < 4; ++q) {
        const int m = m0 + 16*r + (lane>>4)*4 + q;
        const int n = n0 + 16*cc + (lane&15);
        if constexpr (MODE == M_GH) {
          float v = expf(-fmaxf(acc[r][cc][q] + p.b_gh[n], 0.f));
          p.gammah[(size_t)m*512 + n] = f2b(v);
        } else {
          float v = sigf(acc[r][cc][q] + p.b_comb[n]);
          p.beta[(size_t)m*256 + n] = f2b(v);
        }
      }
}

// ---------------- weight conversion / den ----------------
constexpr int CV_TOT = 131072+131072+65536+131072+1048576+1048576; // 2554944
__global__ __launch_bounds__(256) void k_conv(
    const float* Wgh, const float* Whist, const float* Wfr, const float* Wcomb,
    const float* Wih, const float* Whh,
    u16* ogh, u16* ohist, u16* ofr, u16* ocomb, u16* oih, u16* ohh)
{
  int i = blockIdx.x*256 + threadIdx.x;
  if (i >= CV_TOT) return;
  int j = i;
  if (j < 131072) { ogh[j] = f2b(Wgh[j]); return; }       j -= 131072;
  if (j < 131072) { ohist[j] = f2b(Whist[j]); return; }   j -= 131072;
  if (j < 65536)  { ofr[j] = ((j>>8)==(j&255)) ? (u16)0 : f2b(Wfr[j]); return; } j -= 65536;
  if (j < 131072) { ocomb[j] = f2b(Wcomb[j]); return; }   j -= 131072;
  if (j < 1048576){ oih[j] = f2b(Wih[j]); return; }       j -= 1048576;
  ohh[j] = f2b(Whh[j]);
}

__global__ __launch_bounds__(256) void k_den(const float* __restrict__ mask, float* den)
{
  const int t = blockIdx.x;
  float s = 0.f;
  for (int b = 0; b < Bb; ++b)
    s += mask[(size_t)b*TF + (size_t)t*256 + threadIdx.x];
  __shared__ float red[4];
  #pragma unroll
  for (int o = 32; o; o >>= 1) s += __shfl_down(s, o);
  if ((threadIdx.x & 63) == 0) red[threadIdx.x >> 6] = s;
  __syncthreads();
  if (threadIdx.x == 0) den[t] = red[0]+red[1]+red[2]+red[3];
}

__global__ void k_final(const float* num, const float* den, float* out)
{
  if (threadIdx.x < 64) {
    int t = threadIdx.x;
    float s = num[t]/(den[t]+1e-12f) + num[t+64]/(den[t+64]+1e-12f);
    #pragma unroll
    for (int o = 32; o; o >>= 1) s += __shfl_down(s, o);
    if (t == 0) { out[OFF_LOSS] = s; out[OFF_LOSS+1] = 0.f; }
  }
}

// ---------------- persistent recurrence kernel ----------------
struct PP {
  const float *x, *mask;
  const float *b_hist, *b_fr, *b_ih, *b_hh;
  const u16 *Whist, *Wfr, *Wih, *Whh;
  const u16 *gammah, *beta;
  u16 *hdec0, *hdec1, *ximp;
  float *c, *num;
  float *out;
  unsigned *bar;
};

constexpr int NB = 128;   // persistent grid size (must match launch)

__device__ __forceinline__ void gbar(unsigned* bar, unsigned target) {
  __syncthreads();
  if (threadIdx.x == 0) {
    __threadfence();
    __hip_atomic_fetch_add(bar, 1u, __ATOMIC_RELEASE, __HIP_MEMORY_SCOPE_AGENT);
    while (__hip_atomic_load(bar, __ATOMIC_ACQUIRE, __HIP_MEMORY_SCOPE_AGENT) < target)
      __builtin_amdgcn_s_sleep(4);
    __threadfence();
  }
  __syncthreads();
}

__global__ __launch_bounds__(512) void k_loop(PP p)
{
  __shared__ char smem[33792];
  u16*   xr_s  = (u16*)smem;    // phase A: [32][264] bf16 (padded stride)
  float* pre_s = (float*)smem;  // phase B: [8][32][33] f32

  const int tid  = threadIdx.x;
  const int lane = tid & 63, w = tid >> 6;
  const int fr   = lane & 15;
  const int kg   = (lane >> 4) << 3;
  const int bid  = blockIdx.x;
  unsigned ph = 0;

  u16* hr = p.hdec0;
  u16* hw = p.hdec1;

  for (int t = 0; t < Tt; ++t) {
    // ===== phase A: blocks 0..7, each owns 32 rows x all 256 cols =====
    if (bid < 8) {
      const int m0 = bid * 32;
      const int n0 = w * 32;           // 8 waves cover N=256
      // --- XH: x_h = hdec @ Whist^T + b_hist (K=512) ---
      f32x4 acc[2][2] = {};
      for (int k = 0; k < 512; k += 32) {
        const int kk = k + kg;
        bf16x8 a[2], b[2];
        #pragma unroll
        for (int r = 0; r < 2; ++r) a[r] = ldb8(hr + (size_t)(m0+16*r+fr)*512 + kk);
        #pragma unroll
        for (int cc = 0; cc < 2; ++cc) b[cc] = ldb8(p.Whist + (size_t)(n0+16*cc+fr)*512 + kk);
        #pragma unroll
        for (int r = 0; r < 2; ++r)
          #pragma unroll
          for (int cc = 0; cc < 2; ++cc)
            acc[r][cc] = mfma16(a[r], b[cc], acc[r][cc]);
      }
      float xhv[16];
      {
        int ei = 0;
        #pragma unroll
        for (int r = 0; r < 2; ++r)
          #pragma unroll
          for (int cc = 0; cc < 2; ++cc)
            #pragma unroll
            for (int q = 0; q < 4; ++q, ++ei) {
              const int mi = 16*r + (lane>>4)*4 + q;
              const int n  = n0 + 16*cc + (lane&15);
              const float v = acc[r][cc][q] + p.b_hist[n];
              xhv[ei] = v;
              const size_t gi = (size_t)(m0+mi)*TF + (size_t)t*256 + n;
              const float mm = p.mask[gi];
              xr_s[mi*264 + n] = f2b(mm*p.x[gi] + (1.f-mm)*v);
            }
      }
      __syncthreads();
      // --- XU: xu = xr @ Wfr_m^T + b_fr (K=256, A from LDS) ---
      f32x4 acc2[2][2] = {};
      for (int k = 0; k < 256; k += 32) {
        const int kk = k + kg;
        bf16x8 a[2], b[2];
        #pragma unroll
        for (int r = 0; r < 2; ++r) a[r] = *(const bf16x8*)(xr_s + (16*r+fr)*264 + kk);
        #pragma unroll
        for (int cc = 0; cc < 2; ++cc) b[cc] = ldb8(p.Wfr + (size_t)(n0+16*cc+fr)*256 + kk);
        #pragma unroll
        for (int r = 0; r < 2; ++r)
          #pragma unroll
          for (int cc = 0; cc < 2; ++cc)
            acc2[r][cc] = mfma16(a[r], b[cc], acc2[r][cc]);
      }
      float lnum = 0.f;
      {
        int ei = 0;
        #pragma unroll
        for (int r = 0; r < 2; ++r)
          #pragma unroll
          for (int cc = 0; cc < 2; ++cc)
            #pragma unroll
            for (int q = 0; q < 4; ++q, ++ei) {
              const int mi = 16*r + (lane>>4)*4 + q;
              const int n  = n0 + 16*cc + (lane&15);
              const int m  = m0 + mi;
              const float xu  = acc2[r][cc][q] + p.b_fr[n];
              const float bet = b2f(p.beta[((size_t)m*128 + t)*256 + n]);
              const float xc  = bet*xu + (1.f-bet)*xhv[ei];
              const size_t gi = (size_t)m*TF + (size_t)t*256 + n;
              const float mm = p.mask[gi], xx = p.x[gi];
              p.out[OFF_RECON + gi] = xc;
              const float xi = mm*xx + (1.f-mm)*xc;
              p.out[gi] = xi;
              p.ximp[(size_t)m*256 + n] = f2b(xi);
              lnum += fabsf(xc - xx)*mm;
            }
      }
      #pragma unroll
      for (int o = 32; o; o >>= 1) lnum += __shfl_down(lnum, o);
      if (lane == 0) atomicAdd(p.num + t, lnum);
    }
    ph += 1; gbar(p.bar, ph * NB);

    // ===== phase B: all 128 blocks, gates + LSTM =====
    {
      const int mt = bid >> 4, nt = bid & 15;
      const int m0 = mt * 32, n0 = nt * 32;       // n0: per-gate col
      const int g = w & 3, kh = w >> 2;           // wave = (gate, K-half)
      const u16* Wg = kh ? p.Whh : p.Wih;
      f32x4 acc[2][2] = {};
      for (int k = 0; k < 512; k += 32) {
        const int kk = k + kg;
        bf16x8 a[2], b[2];
        #pragma unroll
        for (int r = 0; r < 2; ++r) {
          const int mr = m0 + 16*r + fr;
          if (kh == 0)
            a[r] = (kk < 256) ? ldb8(p.ximp + (size_t)mr*256 + kk)
                              : cvt8(p.mask + (size_t)mr*TF + (size_t)t*256 + (kk-256));
          else
            a[r] = ldb8(hr + (size_t)mr*512 + kk);
        }
        #pragma unroll
        for (int cc = 0; cc < 2; ++cc)
          b[cc] = ldb8(Wg + (size_t)(g*512 + n0 + 16*cc + fr)*512 + kk);
        #pragma unroll
        for (int r = 0; r < 2; ++r)
          #pragma unroll
          for (int cc = 0; cc < 2; ++cc)
            acc[r][cc] = mfma16(a[r], b[cc], acc[r][cc]);
      }
      #pragma unroll
      for (int r = 0; r < 2; ++r)
        #pragma unroll
        for (int cc = 0; cc < 2; ++cc)
          #pragma unroll
          for (int q = 0; q < 4; ++q) {
            const int mi = 16*r + (lane>>4)*4 + q;
            const int ni = 16*cc + (lane&15);
            pre_s[w*1056 + mi*33 + ni] = acc[r][cc][q];
          }
      __syncthreads();
      // fused LSTM (each thread: 2 elements)
      #pragma unroll
      for (int e = tid; e < 1024; e += 512) {
        const int mi = e >> 5, ni = e & 31;
        const int m = m0 + mi, n = n0 + ni;
        float pg[4];
        #pragma unroll
        for (int g2 = 0; g2 < 4; ++g2)
          pg[g2] = pre_s[g2*1056 + mi*33 + ni] + pre_s[(g2+4)*1056 + mi*33 + ni]
                 + p.b_ih[g2*512 + n] + p.b_hh[g2*512 + n];
        const float ig = sigf(pg[0]), fg = sigf(pg[1]);
        const float gg = tanhf(pg[2]), og = sigf(pg[3]);
        const int idx = m*512 + n;
        const float cv = fg*p.c[idx] + ig*gg;
        p.c[idx] = cv;
        const float hv = og*tanhf(cv);
        if (t == Tt-1) p.out[OFF_H + idx] = hv;
        else hw[idx] = f2b(hv * b2f(p.gammah[((size_t)m*128 + t+1)*512 + n]));
      }
    }
    ph += 1; gbar(p.bar, ph * NB);
    u16* tmp = hr; hr = hw; hw = tmp;
  }
}

extern "C" void kernel_launch(void* const* d_in, const int* in_sizes, int n_in,
                              void* d_out, int out_size, void* d_ws, size_t ws_size,
                              hipStream_t stream)
{
  char* wsb = (char*)d_ws;
  u16*  hdec0  = (u16*)(wsb + 0);          //   262144
  u16*  hdec1  = (u16*)(wsb + 262144);     //   262144
  float* c     = (float*)(wsb + 524288);   //   524288
  float* num   = (float*)(wsb + 1048576);  //      512
  unsigned* bar= (unsigned*)(wsb + 1049088); //    256   (memset through 1049344)
  float* den   = (float*)(wsb + 1049344);  //      512
  u16*  ximp   = (u16*)(wsb + 1049856);    //   131072
  u16*  beta   = (u16*)(wsb + 1180928);    // 16777216
  u16*  gammah = (u16*)(wsb + 17958144);   // 33554432
  u16*  Wgh    = (u16*)(wsb + 51512576);   //   262144
  u16*  Whist  = (u16*)(wsb + 51774720);   //   262144
  u16*  Wfr    = (u16*)(wsb + 52036864);   //   131072
  u16*  Wcomb  = (u16*)(wsb + 52167936);   //   262144
  u16*  Wih    = (u16*)(wsb + 52430080);   //  2097152
  u16*  Whh    = (u16*)(wsb + 54527232);   //  2097152  -> total 56624384 B

  // zero hdec0/1, c, num, bar on every (graph-replayed) call
  hipMemsetAsync(d_ws, 0, 1049344, stream);

  k_conv<<<dim3((CV_TOT+255)/256), dim3(256), 0, stream>>>(
      (const float*)d_in[3], (const float*)d_in[7], (const float*)d_in[9],
      (const float*)d_in[11], (const float*)d_in[13], (const float*)d_in[15],
      Wgh, Whist, Wfr, Wcomb, Wih, Whh);
  k_den<<<dim3(128), dim3(256), 0, stream>>>((const float*)d_in[1], den);

  P p{};
  p.x = (const float*)d_in[0];  p.mask = (const float*)d_in[1];
  p.deltas = (const float*)d_in[2];
  p.b_gh = (const float*)d_in[4];  p.w_gx = (const float*)d_in[5];
  p.b_gx = (const float*)d_in[6];  p.b_comb = (const float*)d_in[12];
  p.Wgh = Wgh; p.Wcomb = Wcomb;
  p.gammah = gammah; p.beta = beta;
  gk<M_GH><<<dim3(8, 512), dim3(256), 0, stream>>>(p);    // gamma_h for all t
  gk<M_BETA><<<dim3(4, 512), dim3(256), 0, stream>>>(p);  // beta for all t

  PP q{};
  q.x = (const float*)d_in[0];  q.mask = (const float*)d_in[1];
  q.b_hist = (const float*)d_in[8];  q.b_fr = (const float*)d_in[10];
  q.b_ih = (const float*)d_in[14];   q.b_hh = (const float*)d_in[16];
  q.Whist = Whist; q.Wfr = Wfr; q.Wih = Wih; q.Whh = Whh;
  q.gammah = gammah; q.beta = beta;
  q.hdec0 = hdec0; q.hdec1 = hdec1; q.ximp = ximp;
  q.c = c; q.num = num; q.out = (float*)d_out; q.bar = bar;
  k_loop<<<dim3(NB), dim3(512), 0, stream>>>(q);

  k_final<<<dim3(1), dim3(64), 0, stream>>>(num, den, (float*)d_out);
}